// Round 1
// baseline (356.867 us; speedup 1.0000x reference)
//
#include <hip/hip_runtime.h>
#include <hip/hip_bf16.h>

// Problem constants (B,S,D,H,DK) = (2,2048,1024,16,64), fp32 in/out.
#define NB 2
#define NS 2048
#define ND 1024
#define NH 16
#define NDK 64

typedef __attribute__((ext_vector_type(4))) float f32x4;
typedef __attribute__((ext_vector_type(8))) short bf16x8;

// async global->LDS, 16B per lane (dest = wave-uniform base + lane*16)
__device__ __forceinline__ void async16(const void* g, void* l) {
  __builtin_amdgcn_global_load_lds(
      (const __attribute__((address_space(1))) unsigned int*)g,
      (__attribute__((address_space(3))) unsigned int*)l, 16, 0, 0);
}

// fp32 -> bf16 RNE
__device__ __forceinline__ short f2b(float f) {
  union { float f; unsigned u; } v;
  v.f = f;
  unsigned r = v.u + 0x7FFFu + ((v.u >> 16) & 1u);
  return (short)(r >> 16);
}

// ---------------------------------------------------------------------------
// prep: cast x and weights to bf16, build RoPE tables cos/sin [S][32]
// ---------------------------------------------------------------------------
__global__ void prep_k(const float* __restrict__ x,
                       const float* __restrict__ Wq, const float* __restrict__ Wk,
                       const float* __restrict__ Wv, const float* __restrict__ Wo,
                       const int* __restrict__ pos,
                       short* __restrict__ xb,
                       short* __restrict__ wqb, short* __restrict__ wkb,
                       short* __restrict__ wvb, short* __restrict__ wob,
                       float* __restrict__ cosT, float* __restrict__ sinT) {
  const int stride = gridDim.x * blockDim.x;
  const int tid = blockIdx.x * blockDim.x + threadIdx.x;
  for (int i = tid; i < NB * NS * ND; i += stride) xb[i] = f2b(x[i]);
  for (int i = tid; i < ND * ND; i += stride) {
    wqb[i] = f2b(Wq[i]); wkb[i] = f2b(Wk[i]);
    wvb[i] = f2b(Wv[i]); wob[i] = f2b(Wo[i]);
  }
  for (int i = tid; i < NS * 32; i += stride) {
    const int s = i >> 5, j = i & 31;
    // inv_freq = 1/theta^(2*(j/64)) = theta^(-j/32), matching the fp32 ref
    const float inv = 1.0f / powf(10000.0f, (float)j * (1.0f / 32.0f));
    const float a = (float)pos[s] * inv;
    cosT[i] = cosf(a);
    sinT[i] = sinf(a);
  }
}

// ---------------------------------------------------------------------------
// GEMM: C[m,n] = sum_k A[m,k]*W[n,k];  M=4096, N=1024, K=1024, bf16 MFMA.
// mode 0: RoPE epilogue -> Ob[b,h,s,d]   (Q or K)
// mode 2: transpose epilogue -> Ob[b,h,d,s]  (V)
// mode 3: fp32 epilogue -> Of[m*1024+n]      (output projection)
// 128x128 block tile, BK=32, 4 waves (2x2), each wave 4x4 frags of 16x16.
// ---------------------------------------------------------------------------
__global__ __launch_bounds__(256) void gemm_k(
    const short* __restrict__ A, const short* __restrict__ W,
    short* __restrict__ Ob, float* __restrict__ Of,
    const float* __restrict__ cosT, const float* __restrict__ sinT,
    int mode) {
  __shared__ short As[128 * 32];
  __shared__ short Bs[128 * 32];
  const int tid = threadIdx.x;
  const int lane = tid & 63, wid = tid >> 6;
  const int quad = lane >> 4, l15 = lane & 15;
  const int m0 = blockIdx.x * 128, n0 = blockIdx.y * 128;
  const int wm = (wid & 1) * 64, wn = (wid >> 1) * 64;

  f32x4 acc[4][4] = {};

  // staging: 512 chunks of 16B per tile; thread t does chunks t and t+256
  const int ar = tid >> 2, ac = (tid & 3) << 3;
  const short* Ag = A + (size_t)(m0 + ar) * ND + ac;
  const short* Wg = W + (size_t)(n0 + ar) * ND + ac;

  for (int k0 = 0; k0 < ND; k0 += 32) {
    __syncthreads();                      // prior compute done reading LDS
    async16(Ag + k0, As + tid * 8);
    async16(Ag + 64 * ND + k0, As + 2048 + tid * 8);
    async16(Wg + k0, Bs + tid * 8);
    async16(Wg + 64 * ND + k0, Bs + 2048 + tid * 8);
    __syncthreads();                      // staging complete (vmcnt drained)

    bf16x8 af[4], bf[4];
#pragma unroll
    for (int i = 0; i < 4; i++) {
      af[i] = *(const bf16x8*)(As + (wm + i * 16 + l15) * 32 + quad * 8);
      bf[i] = *(const bf16x8*)(Bs + (wn + i * 16 + l15) * 32 + quad * 8);
    }
#pragma unroll
    for (int i = 0; i < 4; i++)
#pragma unroll
      for (int j = 0; j < 4; j++)
        acc[i][j] = __builtin_amdgcn_mfma_f32_16x16x32_bf16(af[i], bf[j], acc[i][j], 0, 0, 0);
  }

  // epilogue — C layout: col = lane&15, row = quad*4 + reg (verified m89/m91)
#pragma unroll
  for (int i = 0; i < 4; i++) {
    const int gmB = m0 + wm + i * 16 + quad * 4;
#pragma unroll
    for (int j = 0; j < 4; j++) {
      const int gn = n0 + wn + j * 16 + l15;
      f32x4 v = acc[i][j];
      if (mode == 3) {
#pragma unroll
        for (int r = 0; r < 4; r++)
          Of[(size_t)(gmB + r) * ND + gn] = v[r];
      } else if (mode == 2) {
        const int h = gn >> 6, d = gn & 63;
#pragma unroll
        for (int r = 0; r < 4; r++) {
          const int t = gmB + r, b = t >> 11, s = t & (NS - 1);
          Ob[(size_t)((b * NH + h) * NDK + d) * NS + s] = f2b(v[r]);  // V^T
        }
      } else {
        const int h = gn >> 6, d = gn & 63, jj = d >> 1;
#pragma unroll
        for (int r = 0; r < 4; r++) {
          const int t = gmB + r, b = t >> 11, s = t & (NS - 1);
          const float xv = v[r];
          const float pv = __shfl_xor(xv, 1);   // partner column (d^1)
          const float c = cosT[s * 32 + jj], sn = sinT[s * 32 + jj];
          const float o = (d & 1) ? (pv * sn + xv * c)    // odd:  x1*sin + x2*cos
                                  : (xv * c - pv * sn);   // even: x1*cos - x2*sin
          Ob[(size_t)((b * NH + h) * NS + s) * NDK + d] = f2b(o);
        }
      }
    }
  }
}

// ---------------------------------------------------------------------------
// Flash attention: block = (b,h, 64 queries); 4 waves x 16 queries.
// Loop over 32-key tiles staged in LDS; online softmax; P->LDS->A-frag; PV.
// ---------------------------------------------------------------------------
__global__ __launch_bounds__(256) void attn_k(
    const short* __restrict__ Q, const short* __restrict__ K,
    const short* __restrict__ Vt, short* __restrict__ O) {
  __shared__ short Ks[32 * 64];   // [key][d]
  __shared__ short Vs[64 * 32];   // [d][key]  (from V^T)
  __shared__ short Ps[4 * 16 * 32];  // per-wave P tile
  const int tid = threadIdx.x, lane = tid & 63, wid = tid >> 6;
  const int quad = lane >> 4, l15 = lane & 15;
  const int bh = blockIdx.y;
  const int q0 = blockIdx.x * 64;
  const int qw = q0 + wid * 16;
  const short* Qh = Q + (size_t)bh * NS * NDK;
  const short* Kh = K + (size_t)bh * NS * NDK;
  const short* Vh = Vt + (size_t)bh * NDK * NS;

  // Q A-fragments (held for the whole loop): A[m=l15][k=quad*8+j]
  bf16x8 qf[2];
#pragma unroll
  for (int kc = 0; kc < 2; kc++)
    qf[kc] = *(const bf16x8*)(Qh + (size_t)(qw + l15) * NDK + kc * 32 + quad * 8);

  f32x4 o[4] = {};
  float mrow[4], lrow[4];
#pragma unroll
  for (int r = 0; r < 4; r++) { mrow[r] = -1e30f; lrow[r] = 0.f; }

  const int kend = q0 + 64;
  const int kr = tid >> 3, kc2 = (tid & 7) << 3;  // K tile: 32 rows x 8 chunks
  const int vr = tid >> 2, vc = (tid & 3) << 3;   // V tile: 64 rows x 4 chunks

  for (int k0 = 0; k0 < kend; k0 += 32) {
    __syncthreads();
    async16(Kh + (size_t)(k0 + kr) * NDK + kc2, Ks + tid * 8);
    async16(Vh + (size_t)vr * NS + k0 + vc, Vs + tid * 8);
    __syncthreads();

    // S = Q K^T over d=64 (2 MFMAs per 16-key frag)
    f32x4 sc[2];
#pragma unroll
    for (int ni = 0; ni < 2; ni++) {
      bf16x8 kf0 = *(const bf16x8*)(Ks + (ni * 16 + l15) * 64 + quad * 8);
      bf16x8 kf1 = *(const bf16x8*)(Ks + (ni * 16 + l15) * 64 + 32 + quad * 8);
      f32x4 z = {};
      z = __builtin_amdgcn_mfma_f32_16x16x32_bf16(qf[0], kf0, z, 0, 0, 0);
      z = __builtin_amdgcn_mfma_f32_16x16x32_bf16(qf[1], kf1, z, 0, 0, 0);
      sc[ni] = z;
    }

    // online softmax; row = quad*4+r, col = k0 + ni*16 + l15
    short* Pw = Ps + wid * 512;
    float e0[4], e1[4];
#pragma unroll
    for (int r = 0; r < 4; r++) {
      const int q = qw + quad * 4 + r;
      float x0 = (k0 + l15 <= q) ? sc[0][r] * 0.125f : -1e30f;
      float x1 = (k0 + 16 + l15 <= q) ? sc[1][r] * 0.125f : -1e30f;
      float m = fmaxf(x0, x1);
#pragma unroll
      for (int off = 1; off < 16; off <<= 1) m = fmaxf(m, __shfl_xor(m, off));
      const float mn = fmaxf(mrow[r], m);
      const float al = __expf(mrow[r] - mn);
      const float a0 = __expf(x0 - mn), a1 = __expf(x1 - mn);
      float sm = a0 + a1;
#pragma unroll
      for (int off = 1; off < 16; off <<= 1) sm += __shfl_xor(sm, off);
      lrow[r] = lrow[r] * al + sm;
      mrow[r] = mn;
#pragma unroll
      for (int nd = 0; nd < 4; nd++) o[nd][r] *= al;   // rescale O
      e0[r] = a0; e1[r] = a1;
    }

    // P (C-layout) -> LDS -> A-operand layout (per-wave region, in-wave sync)
#pragma unroll
    for (int r = 0; r < 4; r++) {
      Pw[(quad * 4 + r) * 32 + l15] = f2b(e0[r]);
      Pw[(quad * 4 + r) * 32 + 16 + l15] = f2b(e1[r]);
    }
    asm volatile("s_waitcnt lgkmcnt(0)" ::: "memory");
    bf16x8 pf = *(const bf16x8*)(Pw + l15 * 32 + quad * 8);

    // O += P @ V ; B-operand lane n=d holds V^T[d][k0+quad*8..]
#pragma unroll
    for (int nd = 0; nd < 4; nd++) {
      bf16x8 vf = *(const bf16x8*)(Vs + (nd * 16 + l15) * 32 + quad * 8);
      o[nd] = __builtin_amdgcn_mfma_f32_16x16x32_bf16(pf, vf, o[nd], 0, 0, 0);
    }
  }

  // write O[b, s, h*64+d] (merged heads), normalized by l
  const int b = bh >> 4, h = bh & (NH - 1);
#pragma unroll
  for (int nd = 0; nd < 4; nd++)
#pragma unroll
    for (int r = 0; r < 4; r++) {
      const int q = qw + quad * 4 + r;
      O[(size_t)(b * NS + q) * ND + h * NDK + nd * 16 + l15] =
          f2b(o[nd][r] / lrow[r]);
    }
}

// ---------------------------------------------------------------------------
extern "C" void kernel_launch(void* const* d_in, const int* in_sizes, int n_in,
                              void* d_out, int out_size, void* d_ws, size_t ws_size,
                              hipStream_t stream) {
  const float* x  = (const float*)d_in[0];
  const int* pos  = (const int*)d_in[1];
  const float* Wq = (const float*)d_in[2];
  const float* Wk = (const float*)d_in[3];
  const float* Wv = (const float*)d_in[4];
  const float* Wo = (const float*)d_in[5];
  float* out = (float*)d_out;

  // workspace layout (shorts): xb | wq | wk | wv | wo | Qr | Kr | Vt | tables
  short* xb  = (short*)d_ws;          // 4M shorts; reused as attn output O
  short* wqb = xb + 4194304;
  short* wkb = wqb + 1048576;
  short* wvb = wkb + 1048576;
  short* wob = wvb + 1048576;
  short* Qr  = wob + 1048576;
  short* Kr  = Qr + 4194304;
  short* Vt  = Kr + 4194304;
  float* cosT = (float*)(Vt + 4194304);
  float* sinT = cosT + NS * 32;

  prep_k<<<dim3(1024), dim3(256), 0, stream>>>(x, Wq, Wk, Wv, Wo, pos,
                                               xb, wqb, wkb, wvb, wob, cosT, sinT);
  dim3 gg(32, 8), bb(256);
  gemm_k<<<gg, bb, 0, stream>>>(xb, wqb, Qr, nullptr, cosT, sinT, 0);  // Q + RoPE
  gemm_k<<<gg, bb, 0, stream>>>(xb, wkb, Kr, nullptr, cosT, sinT, 0);  // K + RoPE
  gemm_k<<<gg, bb, 0, stream>>>(xb, wvb, Vt, nullptr, cosT, sinT, 2);  // V^T
  attn_k<<<dim3(32, 32), bb, 0, stream>>>(Qr, Kr, Vt, xb);             // O -> xb
  gemm_k<<<gg, bb, 0, stream>>>(xb, wob, nullptr, out, cosT, sinT, 3); // O @ Wo^T
}